// Round 5
// baseline (67896.008 us; speedup 1.0000x reference)
//
#include <hip/hip_runtime.h>
#include <math.h>

// =====================================================================
// AttendAndSpell v4: single persistent kernel, hand-rolled global barrier
// (distributed arrival lines + generation broadcast; cg::grid.sync was
// ~40us/sync in round 3). 3 barriers/step:
//   P1: per-batch fused [sqt quarters via per-b flag | logits+threefry
//       sample | flash-attention quarters | last-of-4 combines ctx]
//   P2: LSTM0 full-K GEMM + cell epilogue (wave = K-half, scalar W rows)
//   P3: LSTM1 ditto (+ writes s1 in both [d][b] and [b][d] layouts)
// All fp32. Memory-ordering pattern mirrors round-3's HW-validated one.
// =====================================================================

#define B_   128
#define HID_ 512
#define VOC_ 64
#define T_   128
#define NCU_ 256

// workspace offsets (floats)
#define S0T_OFF    0u          // 2 bufs 65536
#define S1T_OFF    196608u     // 2 bufs (CS0 at 131072)
#define CS0_OFF    131072u
#define CS1_OFF    327680u
#define S1R_OFF    393216u     // 2 bufs [b][512]
#define SQTB_OFF   524288u     // [b][512]
#define CTXT_OFF   589824u     // [d][128]
#define AA_OFF     655360u     // [q][b][512]
#define AM_OFF     917504u     // [q*128+b]
#define AL_OFF     918016u
#define AMAT_OFF   918528u     // [d][k]
#define W1PSI_OFF  1180672u    // [j][k]
#define BIAS0_OFF  2229248u
#define BIAS1_OFF  2231296u
#define VVEC_OFF   2233344u
#define WOHT_OFF   2233856u    // [j][64]
#define Z_OFF      2364928u    // 128 ints
#define SYNC_OFF   2365056u    // 16384 u32
// sync layout (u32): acnt[i]=i*32 (i<64); agen=2048; bsq[b]=4096+b*32;
// bat[b]=12288+b*32

#define TF_TINY 1.17549435e-38f

__device__ __forceinline__ void tf2x32(unsigned k0, unsigned k1,
                                       unsigned& x0, unsigned& x1) {
  unsigned ks2 = k0 ^ k1 ^ 0x1BD11BDAu;
  const unsigned ks[3] = {k0, k1, ks2};
  const int rot0[4] = {13, 15, 26, 6};
  const int rot1[4] = {17, 29, 16, 24};
  x0 += ks[0]; x1 += ks[1];
  #pragma unroll
  for (int i = 0; i < 5; ++i) {
    #pragma unroll
    for (int r = 0; r < 4; ++r) {
      int rr = (i & 1) ? rot1[r] : rot0[r];
      x0 += x1;
      x1 = (x1 << rr) | (x1 >> (32 - rr));
      x1 ^= x0;
    }
    x0 += ks[(i + 1) % 3];
    x1 += ks[(i + 2) % 3] + (unsigned)(i + 1);
  }
}

__device__ __forceinline__ float bits_to_unit(unsigned bits) {
  return __uint_as_float((bits >> 9) | 0x3f800000u) - 1.0f;
}

__device__ __forceinline__ float sigm(float x) { return 1.0f / (1.0f + expf(-x)); }

// ----------------------- one-time precompute ---------------------------
__global__ __launch_bounds__(256) void k_fold(
    const float* __restrict__ psi_w, const float* __restrict__ phi_b,
    const float* __restrict__ w_ih0, const float* __restrict__ psi_b,
    const float* __restrict__ b_ih0, const float* __restrict__ b_hh0,
    const float* __restrict__ b_ih1, const float* __restrict__ b_hh1,
    float* __restrict__ vvec, float* __restrict__ bias0,
    float* __restrict__ bias1, float* __restrict__ wohT) {
  int gid = blockIdx.x * 256 + threadIdx.x;
  if (gid < 512) {
    float acc = 0.f;
    for (int j = 0; j < 512; ++j) acc += psi_w[j * 512 + gid] * phi_b[j];
    vvec[gid] = acc;
  } else if (gid < 2560) {
    int j = gid - 512;
    float acc = b_ih0[j] + b_hh0[j];
    const float* wr = w_ih0 + (size_t)j * 576 + 64;
    for (int d = 0; d < 512; ++d) acc += wr[d] * psi_b[d];
    bias0[j] = acc;
  } else if (gid < 4608) {
    int j = gid - 2560;
    bias1[j] = b_ih1[j] + b_hh1[j];
  } else if (gid < 4608 + 131072) {
    int idx = gid - 4608;
    int j = idx >> 6, v = idx & 63;
    wohT[idx] = w_ih0[(size_t)j * 576 + v];
  }
}

__global__ __launch_bounds__(256) void k_gemm_tn(
    const float* __restrict__ A, const float* __restrict__ B, float* __restrict__ C,
    int K, int lda, int ldb, int ldc) {
  __shared__ float As[32][33], Bs[32][33];
  int n0 = blockIdx.x * 32, m0 = blockIdx.y * 32;
  int t = threadIdx.x, tx = t & 31, ty = t >> 5;
  float acc[4] = {0.f, 0.f, 0.f, 0.f};
  for (int k0 = 0; k0 < K; k0 += 32) {
    for (int l = t; l < 1024; l += 256) {
      int jj = l >> 5, mm = l & 31;
      As[jj][mm] = A[(size_t)(k0 + jj) * lda + m0 + mm];
      Bs[jj][mm] = B[(size_t)(k0 + jj) * ldb + n0 + mm];
    }
    __syncthreads();
    #pragma unroll 8
    for (int jj = 0; jj < 32; ++jj) {
      float bv = Bs[jj][tx];
      #pragma unroll
      for (int q = 0; q < 4; ++q) acc[q] += As[jj][ty + 8 * q] * bv;
    }
    __syncthreads();
  }
  #pragma unroll
  for (int q = 0; q < 4; ++q) C[(size_t)(m0 + ty + 8 * q) * ldc + n0 + tx] = acc[q];
}

__global__ __launch_bounds__(256) void k_gemm_nn(
    const float* __restrict__ A, const float* __restrict__ B, float* __restrict__ C,
    int K, int lda, int aoff, int ldb, int ldc) {
  __shared__ float As[32][33], Bs[32][33];
  int n0 = blockIdx.x * 32, m0 = blockIdx.y * 32;
  int t = threadIdx.x, tx = t & 31, ty = t >> 5;
  float acc[4] = {0.f, 0.f, 0.f, 0.f};
  for (int k0 = 0; k0 < K; k0 += 32) {
    for (int l = t; l < 1024; l += 256) {
      int r = l >> 5, c = l & 31;
      As[c][r] = A[(size_t)(m0 + r) * lda + aoff + k0 + c];
      Bs[r][c] = B[(size_t)(k0 + r) * ldb + n0 + c];
    }
    __syncthreads();
    #pragma unroll 8
    for (int kk = 0; kk < 32; ++kk) {
      float bv = Bs[kk][tx];
      #pragma unroll
      for (int q = 0; q < 4; ++q) acc[q] += As[kk][ty + 8 * q] * bv;
    }
    __syncthreads();
  }
  #pragma unroll
  for (int q = 0; q < 4; ++q) C[(size_t)(m0 + ty + 8 * q) * ldc + n0 + tx] = acc[q];
}

__global__ __launch_bounds__(128) void k_init(const int* __restrict__ y,
                                              int* __restrict__ z) {
  int t = threadIdx.x;
  if (t < 128) z[t] = y[t * (T_ + 1)];
}

// ----------------------- global barrier --------------------------------
__device__ __forceinline__ void gbar(unsigned* sy, unsigned bno) {
  __syncthreads();
  if (threadIdx.x == 0) {
    __threadfence();
    atomicAdd(&sy[(blockIdx.x & 63) << 5], 1u);
    if (blockIdx.x == 0) {
      unsigned long long target = (unsigned long long)gridDim.x * bno;
      for (;;) {
        unsigned long long s = 0;
        #pragma unroll
        for (int i = 0; i < 64; ++i)
          s += __hip_atomic_load(&sy[i << 5], __ATOMIC_RELAXED,
                                 __HIP_MEMORY_SCOPE_AGENT);
        if (s >= target) break;
        __builtin_amdgcn_s_sleep(4);
      }
      __hip_atomic_store(&sy[2048], bno, __ATOMIC_RELEASE,
                         __HIP_MEMORY_SCOPE_AGENT);
    } else {
      while (__hip_atomic_load(&sy[2048], __ATOMIC_ACQUIRE,
                               __HIP_MEMORY_SCOPE_AGENT) < bno)
        __builtin_amdgcn_s_sleep(8);
    }
    __threadfence();
  }
  __syncthreads();
}

// ----------------------- LSTM phase ------------------------------------
// vb = d-pair. 4 waves: (dg = w>>1, q = w&1). q selects (X,W) half of the
// concatenated K=1024. Lane: kp = l&1 (k parity), b4 = (l>>1)*4.
__device__ __forceinline__ void lstm_phase(
    int vb, int t, const float* X0, const float* W0,
    const float* X1, const float* W1, const float* bias,
    const float* wohT, const int* z, float* cT, float* sT,
    float* srow, float* red) {
  int w  = __builtin_amdgcn_readfirstlane(t >> 6);
  int dg = w >> 1, q = w & 1;
  int d  = vb * 2 + dg;
  int l  = t & 63;
  int kp = l & 1;
  int b4 = (l >> 1) * 4;
  const float* X = q ? X1 : X0;
  const float* W = q ? W1 : W0;
  const float* wr0 = W + (size_t)d * 512;
  const float* wr1 = W + (size_t)(512 + d) * 512;
  const float* wr2 = W + (size_t)(1024 + d) * 512;
  const float* wr3 = W + (size_t)(1536 + d) * 512;
  const float* xp  = X + (size_t)kp * 128 + b4;

  float acc[4][4];
  #pragma unroll
  for (int g = 0; g < 4; ++g)
    #pragma unroll
    for (int bb = 0; bb < 4; ++bb) acc[g][bb] = 0.f;

  for (int k = 0; k < 512; k += 4) {
    float4 xa = *(const float4*)(xp + (size_t)k * 128);
    float4 xb = *(const float4*)(xp + (size_t)(k + 2) * 128);
    float4 w0 = *(const float4*)(wr0 + k);
    float4 w1 = *(const float4*)(wr1 + k);
    float4 w2 = *(const float4*)(wr2 + k);
    float4 w3 = *(const float4*)(wr3 + k);
    float wa0 = kp ? w0.y : w0.x, wb0 = kp ? w0.w : w0.z;
    float wa1 = kp ? w1.y : w1.x, wb1 = kp ? w1.w : w1.z;
    float wa2 = kp ? w2.y : w2.x, wb2 = kp ? w2.w : w2.z;
    float wa3 = kp ? w3.y : w3.x, wb3 = kp ? w3.w : w3.z;
    float xaa[4] = {xa.x, xa.y, xa.z, xa.w};
    float xbb[4] = {xb.x, xb.y, xb.z, xb.w};
    #pragma unroll
    for (int bb = 0; bb < 4; ++bb) {
      acc[0][bb] = fmaf(xaa[bb], wa0, acc[0][bb]);
      acc[0][bb] = fmaf(xbb[bb], wb0, acc[0][bb]);
      acc[1][bb] = fmaf(xaa[bb], wa1, acc[1][bb]);
      acc[1][bb] = fmaf(xbb[bb], wb1, acc[1][bb]);
      acc[2][bb] = fmaf(xaa[bb], wa2, acc[2][bb]);
      acc[2][bb] = fmaf(xbb[bb], wb2, acc[2][bb]);
      acc[3][bb] = fmaf(xaa[bb], wa3, acc[3][bb]);
      acc[3][bb] = fmaf(xbb[bb], wb3, acc[3][bb]);
    }
  }
  #pragma unroll
  for (int g = 0; g < 4; ++g)
    #pragma unroll
    for (int bb = 0; bb < 4; ++bb)
      acc[g][bb] += __shfl_xor(acc[g][bb], 1);

  if (q == 1 && kp == 0) {
    #pragma unroll
    for (int g = 0; g < 4; ++g)
      #pragma unroll
      for (int bb = 0; bb < 4; ++bb)
        red[(dg * 4 + g) * 128 + b4 + bb] = acc[g][bb];
  }
  __syncthreads();
  if (q == 0 && kp == 0) {
    #pragma unroll
    for (int g = 0; g < 4; ++g)
      #pragma unroll
      for (int bb = 0; bb < 4; ++bb)
        acc[g][bb] += red[(dg * 4 + g) * 128 + b4 + bb];
    float bi = bias[d], bf = bias[512 + d];
    float bg = bias[1024 + d], bo = bias[1536 + d];
    if (wohT) {
      #pragma unroll
      for (int bb = 0; bb < 4; ++bb) {
        int zb = z[b4 + bb];
        acc[0][bb] += wohT[(size_t)d * 64 + zb];
        acc[1][bb] += wohT[(size_t)(512 + d) * 64 + zb];
        acc[2][bb] += wohT[(size_t)(1024 + d) * 64 + zb];
        acc[3][bb] += wohT[(size_t)(1536 + d) * 64 + zb];
      }
    }
    float4 c = *(float4*)(cT + (size_t)d * 128 + b4);
    float cc[4] = {c.x, c.y, c.z, c.w};
    float cn[4], sn[4];
    #pragma unroll
    for (int bb = 0; bb < 4; ++bb) {
      float ig = sigm(acc[0][bb] + bi);
      float fg = sigm(acc[1][bb] + bf);
      float gg = tanhf(acc[2][bb] + bg);
      float og = sigm(acc[3][bb] + bo);
      cn[bb] = fg * cc[bb] + ig * gg;
      sn[bb] = og * tanhf(cn[bb]);
    }
    *(float4*)(cT + (size_t)d * 128 + b4) = make_float4(cn[0], cn[1], cn[2], cn[3]);
    *(float4*)(sT + (size_t)d * 128 + b4) = make_float4(sn[0], sn[1], sn[2], sn[3]);
    if (srow) {
      #pragma unroll
      for (int bb = 0; bb < 4; ++bb)
        srow[(size_t)(b4 + bb) * 512 + d] = sn[bb];
    }
  }
  __syncthreads();
}

// ----------------------- the persistent kernel -------------------------
__global__ __launch_bounds__(256, 2) void k_persist(
    const float* __restrict__ h, const float* __restrict__ w_hh0,
    const float* __restrict__ w_ih1, const float* __restrict__ w_hh1,
    const float* __restrict__ outw, const float* __restrict__ outb,
    const int* __restrict__ y, float* __restrict__ out, float* __restrict__ ws) {
  __shared__ float smem[5136];   // sl 512 | sq 512 | hs 4096 | es 8 | ps 8
  __shared__ int ltok;
  float* sl = smem;
  float* sq = smem + 512;
  float* hs = smem + 1024;       // also logits red[64], lstm red[1024]
  float* es = smem + 5120;
  float* ps = smem + 5128;

  float* cs0   = ws + CS0_OFF;
  float* cs1   = ws + CS1_OFF;
  float* sqtb  = ws + SQTB_OFF;
  float* ctxT  = ws + CTXT_OFF;
  float* aa    = ws + AA_OFF;
  float* am    = ws + AM_OFF;
  float* al    = ws + AL_OFF;
  float* Amat  = ws + AMAT_OFF;
  float* W1psi = ws + W1PSI_OFF;
  float* bias0 = ws + BIAS0_OFF;
  float* bias1 = ws + BIAS1_OFF;
  float* vvec  = ws + VVEC_OFF;
  float* wohT  = ws + WOHT_OFF;
  int*   z     = (int*)(ws + Z_OFF);
  unsigned* sy  = (unsigned*)(ws + SYNC_OFF);
  unsigned* bsq = sy + 4096;
  unsigned* bat = sy + 12288;

  int blk = blockIdx.x, nb = gridDim.x, t = threadIdx.x;
  unsigned bar = 0;

  for (int st = 0; st < T_; ++st) {
    int p = st & 1;
    const float* s1rP = ws + S1R_OFF + p * 65536;
    float*       s1rN = ws + S1R_OFF + (1 - p) * 65536;
    const float* s0P  = ws + S0T_OFF + p * 65536;
    float*       s0N  = ws + S0T_OFF + (1 - p) * 65536;
    const float* s1P  = ws + S1T_OFF + p * 65536;
    float*       s1N  = ws + S1T_OFF + (1 - p) * 65536;

    // ================= P1 =================
    for (int vb = blk; vb < 512; vb += nb) {
      int b = vb >> 2, q = vb & 3;
      // load s1row[b]
      sl[t]       = s1rP[b * 512 + t];
      sl[t + 256] = s1rP[b * 512 + t + 256];
      __syncthreads();
      // sqt quarter (2 threads per d)
      {
        int dd = q * 128 + (t >> 1);
        int kh = t & 1;
        const float* ar  = Amat + (size_t)dd * 512 + kh * 256;
        const float* slk = sl + kh * 256;
        float s = 0.f;
        #pragma unroll 4
        for (int k = 0; k < 256; k += 4) {
          float4 av = *(const float4*)(ar + k);
          s += av.x * slk[k] + av.y * slk[k + 1] + av.z * slk[k + 2] + av.w * slk[k + 3];
        }
        s += __shfl_xor(s, 1);
        if (kh == 0) sqtb[b * 512 + dd] = s + vvec[dd];
      }
      __syncthreads();
      if (t == 0) { __threadfence(); atomicAdd(&bsq[b], 1u); }
      // logits + sample (block q==1)
      if (q == 1 && st > 0) {
        int v = t >> 2, ks = t & 3;
        const float* wr = outw + (size_t)v * 512 + ks * 128;
        const float* sr = sl + ks * 128;
        float s = 0.f;
        #pragma unroll 8
        for (int k = 0; k < 128; k += 4) {
          float4 w4 = *(const float4*)(wr + k);
          s += w4.x * sr[k] + w4.y * sr[k + 1] + w4.z * sr[k + 2] + w4.w * sr[k + 3];
        }
        s += __shfl_xor(s, 1);
        s += __shfl_xor(s, 2);
        if (ks == 0) hs[v] = s + outb[v];
      }
      __syncthreads();
      if (q == 1 && st > 0 && t < 64) {
        float o = hs[t];
        out[((size_t)b * T_ + (st - 1)) * VOC_ + t] = o;
        unsigned ka = 0u, kb2 = (unsigned)(st - 1);
        tf2x32(0u, 42u, ka, kb2);
        unsigned k1a = 0u, k1b = 0u;
        tf2x32(ka, kb2, k1a, k1b);
        unsigned x0 = 0u, x1 = (unsigned)(b * 64 + t);
        tf2x32(k1a, k1b, x0, x1);
        float f = bits_to_unit(x0 ^ x1);
        float u = fmaxf(TF_TINY, f * (1.0f - TF_TINY) + TF_TINY);
        float val = o - logf(-logf(u));
        int idx = t;
        #pragma unroll
        for (int off = 1; off < 64; off <<= 1) {
          float ov = __shfl_xor(val, off);
          int oi = __shfl_xor(idx, off);
          if (ov > val || (ov == val && oi < idx)) { val = ov; idx = oi; }
        }
        if (t == 0) {
          unsigned k2a = 0u, k2b = 1u;
          tf2x32(ka, kb2, k2a, k2b);
          unsigned y0 = 0u, y1 = (unsigned)b;
          tf2x32(k2a, k2b, y0, y1);
          float ub = bits_to_unit(y0 ^ y1);
          z[b] = (ub < 0.1f) ? idx : y[b * (T_ + 1) + st];
        }
      }
      // wait for full sqt[b]
      if (t == 0) {
        while (__hip_atomic_load(&bsq[b], __ATOMIC_RELAXED,
                                 __HIP_MEMORY_SCOPE_AGENT) < 4u * (st + 1))
          __builtin_amdgcn_s_sleep(8);
        __threadfence();
      }
      __syncthreads();
      sq[t]       = sqtb[b * 512 + t];
      sq[t + 256] = sqtb[b * 512 + t + 256];
      __syncthreads();
      // flash attention over this block's 128-row quarter, 8-row chunks
      int r = t >> 5, g = t & 31;
      const float* hb = h + (size_t)b * 512 * 512;
      float m = -INFINITY, lsum = 0.f, a0 = 0.f, a1 = 0.f;
      for (int r0 = q * 128; r0 < q * 128 + 128; r0 += 8) {
        __syncthreads();
        const float* hr = hb + (size_t)(r0 + r) * 512 + g * 16;
        float ep = 0.f;
        #pragma unroll
        for (int i = 0; i < 4; ++i) {
          float4 hv = *(const float4*)(hr + i * 4);
          float4 sv = *(const float4*)(sq + g * 16 + i * 4);
          ep += hv.x * sv.x + hv.y * sv.y + hv.z * sv.z + hv.w * sv.w;
          *(float4*)(&hs[r * 512 + g * 16 + i * 4]) = hv;
        }
        ep += __shfl_xor(ep, 1);
        ep += __shfl_xor(ep, 2);
        ep += __shfl_xor(ep, 4);
        ep += __shfl_xor(ep, 8);
        ep += __shfl_xor(ep, 16);
        if (g == 0) es[r] = ep;
        __syncthreads();
        float mc = fmaxf(fmaxf(fmaxf(es[0], es[1]), fmaxf(es[2], es[3])),
                         fmaxf(fmaxf(es[4], es[5]), fmaxf(es[6], es[7])));
        float mn = fmaxf(m, mc);
        if (t < 8) ps[t] = expf(es[t] - mn);
        __syncthreads();
        float sc = expf(m - mn), ls = 0.f;
        float n0 = a0 * sc, n1 = a1 * sc;
        #pragma unroll
        for (int k = 0; k < 8; ++k) {
          float pp = ps[k];
          ls += pp;
          n0 += pp * hs[k * 512 + t];
          n1 += pp * hs[k * 512 + t + 256];
        }
        m = mn; lsum = lsum * sc + ls; a0 = n0; a1 = n1;
      }
      aa[(size_t)(q * 128 + b) * 512 + t]       = a0;
      aa[(size_t)(q * 128 + b) * 512 + t + 256] = a1;
      if (t == 0) { am[q * 128 + b] = m; al[q * 128 + b] = lsum; }
      __syncthreads();
      if (t == 0) {
        __threadfence();
        unsigned old = atomicAdd(&bat[b], 1u);
        if (old == 4u * (st + 1) - 1u) { __threadfence(); ltok = 1; }
        else ltok = 0;
      }
      __syncthreads();
      if (ltok) {
        float m0 = am[b], m1 = am[128 + b], m2 = am[256 + b], m3 = am[384 + b];
        float M = fmaxf(fmaxf(m0, m1), fmaxf(m2, m3));
        float e0 = expf(m0 - M), e1 = expf(m1 - M);
        float e2 = expf(m2 - M), e3 = expf(m3 - M);
        float L = e0 * al[b] + e1 * al[128 + b] + e2 * al[256 + b] + e3 * al[384 + b];
        float inv = 1.0f / L;
        float w0 = e0 * inv, w1 = e1 * inv, w2 = e2 * inv, w3 = e3 * inv;
        #pragma unroll
        for (int dh = 0; dh < 2; ++dh) {
          int d = t + dh * 256;
          float v = w0 * aa[(size_t)b * 512 + d]
                  + w1 * aa[(size_t)(128 + b) * 512 + d]
                  + w2 * aa[(size_t)(256 + b) * 512 + d]
                  + w3 * aa[(size_t)(384 + b) * 512 + d];
          ctxT[(size_t)d * 128 + b] = v;
        }
      }
      __syncthreads();
    }
    gbar(sy, ++bar);

    // ================= P2: LSTM0 =================
    for (int vb = blk; vb < 256; vb += nb)
      lstm_phase(vb, t, ctxT, W1psi, s0P, w_hh0, bias0, wohT, z, cs0, s0N,
                 nullptr, hs);
    gbar(sy, ++bar);

    // ================= P3: LSTM1 =================
    for (int vb = blk; vb < 256; vb += nb)
      lstm_phase(vb, t, s0N, w_ih1, s1P, w_hh1, bias1, nullptr, nullptr, cs1,
                 s1N, s1rN, hs);
    gbar(sy, ++bar);
  }

  // final logits (s1 after step 127 lives in row-buffer 0)
  const float* s1rF = ws + S1R_OFF;
  for (int vb = blk; vb < 128; vb += nb) {
    int b = vb;
    sl[t]       = s1rF[b * 512 + t];
    sl[t + 256] = s1rF[b * 512 + t + 256];
    __syncthreads();
    int v = t >> 2, ks = t & 3;
    const float* wr = outw + (size_t)v * 512 + ks * 128;
    const float* sr = sl + ks * 128;
    float s = 0.f;
    #pragma unroll 8
    for (int k = 0; k < 128; k += 4) {
      float4 w4 = *(const float4*)(wr + k);
      s += w4.x * sr[k] + w4.y * sr[k + 1] + w4.z * sr[k + 2] + w4.w * sr[k + 3];
    }
    s += __shfl_xor(s, 1);
    s += __shfl_xor(s, 2);
    if (ks == 0) hs[v] = s + outb[v];
    __syncthreads();
    if (t < 64) out[((size_t)b * T_ + (T_ - 1)) * VOC_ + t] = hs[t];
    __syncthreads();
  }
}

// =====================================================================
extern "C" void kernel_launch(void* const* d_in, const int* in_sizes, int n_in,
                              void* d_out, int out_size, void* d_ws, size_t ws_size,
                              hipStream_t stream) {
  const float* h     = (const float*)d_in[0];
  const float* phi_w = (const float*)d_in[1];
  const float* phi_b = (const float*)d_in[2];
  const float* psi_w = (const float*)d_in[3];
  const float* psi_b = (const float*)d_in[4];
  const float* w_ih0 = (const float*)d_in[5];
  const float* w_hh0 = (const float*)d_in[6];
  const float* b_ih0 = (const float*)d_in[7];
  const float* b_hh0 = (const float*)d_in[8];
  const float* w_ih1 = (const float*)d_in[9];
  const float* w_hh1 = (const float*)d_in[10];
  const float* b_ih1 = (const float*)d_in[11];
  const float* b_hh1 = (const float*)d_in[12];
  const float* out_w = (const float*)d_in[13];
  const float* out_b = (const float*)d_in[14];
  const int*   y     = (const int*)d_in[15];

  float* out = (float*)d_out;
  float* ws  = (float*)d_ws;

  // zero recurrent states + row buffers (0..524288 floats) and sync area
  hipMemsetAsync(ws, 0, 524288u * sizeof(float), stream);
  hipMemsetAsync(ws + SYNC_OFF, 0, 16384u * sizeof(unsigned), stream);

  k_fold<<<531, 256, 0, stream>>>(psi_w, phi_b, w_ih0, psi_b, b_ih0, b_hh0,
                                  b_ih1, b_hh1, ws + VVEC_OFF, ws + BIAS0_OFF,
                                  ws + BIAS1_OFF, ws + WOHT_OFF);
  k_gemm_tn<<<dim3(16, 16), 256, 0, stream>>>(psi_w, phi_w, ws + AMAT_OFF,
                                              512, 512, 512, 512);
  k_gemm_nn<<<dim3(16, 64), 256, 0, stream>>>(w_ih0, psi_w, ws + W1PSI_OFF,
                                              512, 576, 64, 512, 512);
  k_init<<<1, 128, 0, stream>>>(y, (int*)(ws + Z_OFF));

  int maxB = 0;
  hipError_t oe = hipOccupancyMaxActiveBlocksPerMultiprocessor(
      &maxB, (const void*)k_persist, 256, 0);
  int grid = 256;
  if (oe == hipSuccess && maxB >= 1) {
    grid = maxB * NCU_;
    if (grid > 512) grid = 512;
  }

  void* args[] = {(void*)&h, (void*)&w_hh0, (void*)&w_ih1, (void*)&w_hh1,
                  (void*)&out_w, (void*)&out_b, (void*)&y, (void*)&out, (void*)&ws};
  hipLaunchCooperativeKernel((const void*)k_persist, dim3(grid), dim3(256),
                             args, 0, stream);
}